// Round 1
// baseline (28.159 us; speedup 1.0000x reference)
//
#include <hip/hip_runtime.h>

#define NBINS 256
#define NCH 3
#define NWAVES 4          // 256 threads / 64 lanes
#define BLOCK 256
#define ELEMS_PER_THREAD 12   // 3 x float4; 12 % 3 == 0 so channel is compile-time

__global__ __launch_bounds__(BLOCK) void hist_kernel(const float* __restrict__ in,
                                                     unsigned int* __restrict__ counts,
                                                     int blocksPerBatch,
                                                     int floatsPerBatch) {
    __shared__ unsigned int h[NWAVES][NCH * NBINS];

    const int tid = threadIdx.x;
    // zero LDS histograms
    for (int i = tid; i < NWAVES * NCH * NBINS; i += BLOCK) {
        ((unsigned int*)h)[i] = 0u;
    }
    __syncthreads();

    const int b     = blockIdx.x / blocksPerBatch;
    const int chunk = blockIdx.x % blocksPerBatch;
    const int chunkFloats = floatsPerBatch / blocksPerBatch;      // 24576
    const float* base = in + (size_t)b * floatsPerBatch + (size_t)chunk * chunkFloats;
    const int w = tid >> 6;

    const int floatsPerIter = BLOCK * ELEMS_PER_THREAD;           // 3072
    const int iters = chunkFloats / floatsPerIter;                // 8

    for (int it = 0; it < iters; ++it) {
        const float4* p = (const float4*)(base + (size_t)it * floatsPerIter
                                               + (size_t)tid * ELEMS_PER_THREAD);
        float4 v0 = p[0];
        float4 v1 = p[1];
        float4 v2 = p[2];
        float v[ELEMS_PER_THREAD] = {v0.x, v0.y, v0.z, v0.w,
                                     v1.x, v1.y, v1.z, v1.w,
                                     v2.x, v2.y, v2.z, v2.w};
#pragma unroll
        for (int j = 0; j < ELEMS_PER_THREAD; ++j) {
            int bin = (int)floorf(v[j] * 256.0f);
            bin = bin < 0 ? 0 : (bin > NBINS - 1 ? NBINS - 1 : bin);
            const int c = j % NCH;   // compile-time constant under unroll
            atomicAdd(&h[w][c * NBINS + bin], 1u);
        }
    }
    __syncthreads();

    // reduce the 4 wave-private copies and accumulate to global
    unsigned int* dst = counts + (size_t)b * (NCH * NBINS);
    for (int i = tid; i < NCH * NBINS; i += BLOCK) {
        unsigned int s = h[0][i] + h[1][i] + h[2][i] + h[3][i];
        if (s) atomicAdd(&dst[i], s);
    }
}

__global__ __launch_bounds__(BLOCK) void finalize_kernel(const unsigned int* __restrict__ counts,
                                                         float* __restrict__ out,
                                                         int n, float inv_n) {
    int i = blockIdx.x * BLOCK + threadIdx.x;   // index into out[b][bin][c]
    if (i >= n) return;
    int c   = i % NCH;
    int bin = (i / NCH) % NBINS;
    int b   = i / (NCH * NBINS);
    out[i] = (float)counts[(size_t)b * (NCH * NBINS) + c * NBINS + bin] * inv_n;
}

extern "C" void kernel_launch(void* const* d_in, const int* in_sizes, int n_in,
                              void* d_out, int out_size, void* d_ws, size_t ws_size,
                              hipStream_t stream) {
    const float* in = (const float*)d_in[0];
    float* out = (float*)d_out;

    const int floatsPerBatch = 512 * 512 * 3;        // H*W*C
    const int total = in_sizes[0];
    const int B = total / floatsPerBatch;            // 32
    const int n = 512 * 512;                         // per-channel normalizer

    unsigned int* counts = (unsigned int*)d_ws;
    hipMemsetAsync(d_ws, 0, (size_t)B * NCH * NBINS * sizeof(unsigned int), stream);

    const int blocksPerBatch = 32;                   // 1024 blocks total, 8 iters each
    hist_kernel<<<B * blocksPerBatch, BLOCK, 0, stream>>>(in, counts, blocksPerBatch,
                                                          floatsPerBatch);

    const int outN = B * NBINS * NCH;
    finalize_kernel<<<(outN + BLOCK - 1) / BLOCK, BLOCK, 0, stream>>>(
        counts, out, outN, 1.0f / (float)n);
}